// Round 9
// baseline (934.044 us; speedup 1.0000x reference)
//
#include <hip/hip_runtime.h>

#define TT 1024
#define SSZ 1024
#define DD 64
#define BHN 64
#define BSZN 4
#define EEN 1024
#define EPSF 1e-6f

using f32x4 = __attribute__((ext_vector_type(4))) float;
using i32x4 = __attribute__((ext_vector_type(4))) int;
using s16x8 = __attribute__((ext_vector_type(8))) short;

// static buffers (avoid ws_size assumptions)
__device__ unsigned short g_Pb[(size_t)BHN * TT * SSZ];  // bf16 alpha copy (134MB)
__device__ unsigned short g_Vt[(size_t)BHN * DD * SSZ];  // bf16 V^T [bh][d][s] (8MB)
__device__ unsigned short g_Wb[(size_t)EEN * EEN];       // bf16 W [n][k] (2MB)
__device__ unsigned short g_Xb[(size_t)TT * BSZN * EEN]; // bf16 X [t][bz][e] (8MB)

// ---------------- helpers ----------------
template<int CTRL, int RM>
__device__ __forceinline__ float f_dpp(float x, float ident) {
  return __builtin_bit_cast(float,
      __builtin_amdgcn_update_dpp(__builtin_bit_cast(int, ident),
                                  __builtin_bit_cast(int, x),
                                  CTRL, RM, 0xF, false));
}

__device__ __forceinline__ float wscan_add(float x) {
  x += f_dpp<0x111, 0xF>(x, 0.0f);
  x += f_dpp<0x112, 0xF>(x, 0.0f);
  x += f_dpp<0x114, 0xF>(x, 0.0f);
  x += f_dpp<0x118, 0xF>(x, 0.0f);
  x += f_dpp<0x142, 0xA>(x, 0.0f);
  x += f_dpp<0x143, 0xC>(x, 0.0f);
  return x;
}

__device__ __forceinline__ float wave_shr1(float x, float ident) {
  return f_dpp<0x138, 0xF>(x, ident);
}

__device__ __forceinline__ int cvt_pk(float lo, float hi) {
  int r;
  asm("v_cvt_pk_bf16_f32 %0, %1, %2" : "=v"(r) : "v"(lo), "v"(hi));
  return r;
}
__device__ __forceinline__ unsigned short bfr(float x) {  // scalar RTNE bf16
  unsigned u = __builtin_bit_cast(unsigned, x);
  u += 0x7fffu + ((u >> 16) & 1u);
  return (unsigned short)(u >> 16);
}
__device__ __forceinline__ s16x8 pack8p(const float* p) {  // 8 consecutive f32 -> bf16x8
  f32x4 a = *(const f32x4*)p;
  f32x4 b = *(const f32x4*)(p + 4);
  i32x4 r;
  r[0] = cvt_pk(a[0], a[1]); r[1] = cvt_pk(a[2], a[3]);
  r[2] = cvt_pk(b[0], b[1]); r[3] = cvt_pk(b[2], b[3]);
  return __builtin_bit_cast(s16x8, r);
}
__device__ __forceinline__ s16x8 pack8f(float v0, float v1, float v2, float v3,
                                        float v4, float v5, float v6, float v7) {
  i32x4 r;
  r[0] = cvt_pk(v0, v1); r[1] = cvt_pk(v2, v3);
  r[2] = cvt_pk(v4, v5); r[3] = cvt_pk(v6, v7);
  return __builtin_bit_cast(s16x8, r);
}

// asm-pinned vmem/LDS ops: invisible to the compiler's hazard analysis,
// ordered only by OUR fences (vmcnt / lgkmcnt + sched_barrier).
__device__ __forceinline__ void astore(float* p, f32x4 v) {
  asm volatile("global_store_dwordx4 %0, %1, off" :: "v"(p), "v"(v) : "memory");
}
__device__ __forceinline__ void astore4i(unsigned short* p, i32x4 v) {
  asm volatile("global_store_dwordx4 %0, %1, off" :: "v"(p), "v"(v) : "memory");
}
__device__ __forceinline__ f32x4 lds_read16(unsigned byte_off) {
  f32x4 r;
  asm volatile("ds_read_b128 %0, %1" : "=v"(r) : "v"(byte_off));
  return r;
}

// ---------------- prep: W -> bf16 ----------------
__global__ __launch_bounds__(256) void k_prep_w(const float* __restrict__ W) {
  const size_t idx = ((size_t)blockIdx.x * 256 + threadIdx.x) * 8;
  *(s16x8*)(g_Wb + idx) = pack8p(W + idx);
}

// ---------------- prep: V -> bf16 transposed V^T[bh][d][s] ----------------
__global__ __launch_bounds__(256) void k_prep_v(const float* __restrict__ V) {
  __shared__ float tile[64][65];
  const int tid = threadIdx.x;
  const int bh = blockIdx.x >> 4;
  const int s0 = (blockIdx.x & 15) << 6;
  {
    const int r = tid >> 2, cq = (tid & 3) << 4;
    const float* src = V + ((size_t)bh * SSZ + s0 + r) * DD + cq;
    *(float4*)&tile[r][cq + 0]  = *(const float4*)(src + 0);
    *(float4*)&tile[r][cq + 4]  = *(const float4*)(src + 4);
    *(float4*)&tile[r][cq + 8]  = *(const float4*)(src + 8);
    *(float4*)&tile[r][cq + 12] = *(const float4*)(src + 12);
  }
  __syncthreads();
  {
    const int d = tid >> 2, sq = (tid & 3) << 4;
    unsigned short* dst = g_Vt + ((size_t)bh * DD + d) * SSZ + s0 + sq;
    *(s16x8*)(dst + 0) = pack8f(tile[sq + 0][d], tile[sq + 1][d], tile[sq + 2][d], tile[sq + 3][d],
                                tile[sq + 4][d], tile[sq + 5][d], tile[sq + 6][d], tile[sq + 7][d]);
    *(s16x8*)(dst + 8) = pack8f(tile[sq + 8][d], tile[sq + 9][d], tile[sq + 10][d], tile[sq + 11][d],
                                tile[sq + 12][d], tile[sq + 13][d], tile[sq + 14][d], tile[sq + 15][d]);
  }
}

// ---------------- K1: p = sigmoid(Q K^T + bias) via bf16 MFMA ----------------
__global__ __launch_bounds__(256) void k_energy(const float* __restrict__ Q,
                                                const float* __restrict__ Kp,
                                                const float* __restrict__ eb,
                                                float* __restrict__ P) {
  const int tid = threadIdx.x, w = tid >> 6, l = tid & 63;
  const int rl = l & 15, kg = l >> 4;
  const int bh = blockIdx.x >> 6;
  const int tile = blockIdx.x & 63;
  const int m0 = (tile >> 2) << 6;
  const int n0 = (((tile & 3) << 2) + w) << 6;
  const float* qb = Q + (size_t)bh * TT * DD;
  const float* kb = Kp + (size_t)bh * SSZ * DD;

  f32x4 acc[4][4];
#pragma unroll
  for (int i = 0; i < 4; ++i)
#pragma unroll
    for (int j = 0; j < 4; ++j) acc[i][j] = (f32x4)0.0f;

#pragma unroll
  for (int ks = 0; ks < 2; ++ks) {
    const int kof = (ks << 5) + (kg << 3);
    s16x8 af[4], bf[4];
#pragma unroll
    for (int fi = 0; fi < 4; ++fi)
      af[fi] = pack8p(qb + (size_t)(m0 + fi * 16 + rl) * DD + kof);
#pragma unroll
    for (int fj = 0; fj < 4; ++fj)
      bf[fj] = pack8p(kb + (size_t)(n0 + fj * 16 + rl) * DD + kof);
#pragma unroll
    for (int fi = 0; fi < 4; ++fi)
#pragma unroll
      for (int fj = 0; fj < 4; ++fj)
        acc[fi][fj] = __builtin_amdgcn_mfma_f32_16x16x32_bf16(af[fi], bf[fj], acc[fi][fj], 0, 0, 0);
  }

  const float bias = eb[0];
  float* pb = P + (size_t)bh * TT * SSZ;
#pragma unroll
  for (int fi = 0; fi < 4; ++fi)
#pragma unroll
    for (int r = 0; r < 4; ++r) {
      const size_t rowoff = (size_t)(m0 + fi * 16 + (kg << 2) + r) * SSZ;
#pragma unroll
      for (int fj = 0; fj < 4; ++fj) {
        float x = acc[fi][fj][r] + bias;
        pb[rowoff + n0 + fj * 16 + rl] = __builtin_amdgcn_rcpf(1.0f + __expf(-x));
      }
    }
}

// ---------------- K2: single-wave scan; gload_lds ring + asm ds_read (no compiler waits) ----------------
// LDS ring: 8 live slots + 1 dummy (tail clamp). Row r chunk j lane l at
// ring[slot][j*256 + l*4] (HW scatter = uniform base + lane*16B).
// Step t: fence vmcnt(24) (row t's 4 loads have >=70 vmem ops issued after
// them; vmcnt decrements in issue order => retired) -> asm ds_read row t ->
// lgkmcnt(0)+sched_barrier -> issue prefetch row t+8 -> compute -> asm stores.
// All vmem/LDS ops are asm/builtin: compiler's memory legalizer sees nothing
// to conservatively drain (the round-8 608us was its vmcnt(0) before ds_read).
__global__ __launch_bounds__(64, 1) void k_scan(float* __restrict__ A) {
  __shared__ float ring[9][1024];
  const int b = blockIdx.x;
  const int lane = threadIdx.x;
  float* gq = A + (size_t)b * TT * SSZ + (lane << 4);
  unsigned short* gpb = g_Pb + (size_t)b * TT * SSZ + (lane << 4);

  // prologue: stage rows 0..7
#pragma unroll
  for (int r = 0; r < 8; ++r) {
#pragma unroll
    for (int j = 0; j < 4; ++j)
      __builtin_amdgcn_global_load_lds(
          (const __attribute__((address_space(1))) void*)(gq + (size_t)r * SSZ + j * 4),
          (__attribute__((address_space(3))) void*)&ring[r][j * 256], 16, 0, 0);
  }

  // per-lane LDS byte offset of ring[0][lane*4]
  const unsigned lds0 =
      (unsigned)(size_t)(__attribute__((address_space(3))) float*)&ring[0][lane << 2];

  float prev[16];
#pragma unroll
  for (int i = 0; i < 16; ++i) prev[i] = 0.0f;
  if (lane == 0) prev[0] = 1.0f;

  for (int t = 0; t < TT; ++t) {
    asm volatile("s_waitcnt vmcnt(24)" ::: "memory");
    __builtin_amdgcn_sched_barrier(0);
    // row t from slot t&7 (asm ds_read; consumed this step -> no cross-step hazard)
    const unsigned so = lds0 + ((unsigned)(t & 7) << 12);
    f32x4 qc0 = lds_read16(so);
    f32x4 qc1 = lds_read16(so + 1024);
    f32x4 qc2 = lds_read16(so + 2048);
    f32x4 qc3 = lds_read16(so + 3072);
    asm volatile("s_waitcnt lgkmcnt(0)" ::: "memory");
    __builtin_amdgcn_sched_barrier(0);
    // prefetch row t+8 -> slot t&7 (its row t data now in regs). Tail -> dummy
    // slot 8 so live slots never clobbered and load count stays exact.
    {
      int rr = t + 8;
      const int sl = (rr <= TT - 1) ? (t & 7) : 8;
      if (rr > TT - 1) rr = TT - 1;
#pragma unroll
      for (int j = 0; j < 4; ++j)
        __builtin_amdgcn_global_load_lds(
            (const __attribute__((address_space(1))) void*)(gq + (size_t)rr * SSZ + j * 4),
            (__attribute__((address_space(3))) void*)&ring[sl][j * 256], 16, 0, 0);
    }

    // ---- f = 1 - p (row t) ----
    float f[16];
#pragma unroll
    for (int j = 0; j < 4; ++j) {
      f[0 + j]  = 1.0f - qc0[j];
      f[4 + j]  = 1.0f - qc1[j];
      f[8 + j]  = 1.0f - qc2[j];
      f[12 + j] = 1.0f - qc3[j];
    }
    // ---- division-free D-recurrence (round-2 algebra, HW-verified) ----
    float l[16];
    l[0] = f[0];
#pragma unroll
    for (int i = 1; i < 16; ++i) l[i] = l[i - 1] * f[i];
    float fpl = wave_shr1(f[15], 1.0f);
    float al[8]; al[0] = fpl;
#pragma unroll
    for (int i = 1; i < 8; ++i) al[i] = al[i - 1] * f[i - 1];
    float ah[8]; ah[0] = f[7];
#pragma unroll
    for (int j = 1; j < 8; ++j) ah[j] = ah[j - 1] * f[7 + j];
    float A0 = al[7] * ah[7];
    float A1 = A0 * f_dpp<0x111, 0xF>(A0, 1.0f);
    float A2 = A1 * f_dpp<0x112, 0xF>(A1, 1.0f);
    float A3 = A2 * f_dpp<0x114, 0xF>(A2, 1.0f);
    float A4 = A3 * f_dpp<0x118, 0xF>(A3, 1.0f);
    float A5 = A4 * f_dpp<0x142, 0xA>(A4, 1.0f);
    float A6 = A5 * f_dpp<0x143, 0xC>(A5, 1.0f);
    float Aexcl = wave_shr1(A6, 1.0f);
    float wx6 = (Aexcl * fpl) * 1e6f;
    float bb[16];
    bb[0] = fminf(wx6 * prev[0], prev[0]);
#pragma unroll
    for (int i = 1; i < 16; ++i) bb[i] = fminf((wx6 * l[i - 1]) * prev[i], prev[i]);
    float Blo[8]; Blo[0] = bb[0];
#pragma unroll
    for (int i = 1; i < 8; ++i) Blo[i] = fmaf(f[i - 1], Blo[i - 1], bb[i]);
    float Bhi[8]; Bhi[0] = bb[8];
#pragma unroll
    for (int j = 1; j < 8; ++j) Bhi[j] = fmaf(f[7 + j], Bhi[j - 1], bb[8 + j]);
    float B_ = fmaf(ah[7], Blo[7], Bhi[7]);
    B_ = fmaf(A0, f_dpp<0x111, 0xF>(B_, 0.0f), B_);
    B_ = fmaf(A1, f_dpp<0x112, 0xF>(B_, 0.0f), B_);
    B_ = fmaf(A2, f_dpp<0x114, 0xF>(B_, 0.0f), B_);
    B_ = fmaf(A3, f_dpp<0x118, 0xF>(B_, 0.0f), B_);
    B_ = fmaf(A4, f_dpp<0x142, 0xA>(B_, 0.0f), B_);
    B_ = fmaf(A5, f_dpp<0x143, 0xC>(B_, 0.0f), B_);
    float carry = wave_shr1(B_, 0.0f);
    float D[16];
#pragma unroll
    for (int i = 0; i < 8; ++i) D[i] = fmaf(al[i], carry, Blo[i]);
#pragma unroll
    for (int j = 0; j < 8; ++j) D[8 + j] = fmaf(ah[j], D[7], Bhi[j]);
    float a[16];
#pragma unroll
    for (int i = 0; i < 16; ++i) {
      a[i] = fminf(fmaf(-f[i], D[i], D[i]), 1.0f);
      prev[i] = a[i];  // carry PRE-residual alpha
    }
    // ---- residual mass on s = S-1 (store-only) ----
    float s0_ = (a[0] + a[1]) + (a[2] + a[3]);
    float s1_ = (a[4] + a[5]) + (a[6] + a[7]);
    float s2_ = (a[8] + a[9]) + (a[10] + a[11]);
    float s3_ = (a[12] + a[13]) + (a[14] + a[15]);
    float tot = wscan_add((s0_ + s1_) + (s2_ + s3_));
    if (lane == 63)
      a[15] = 1.0f - fminf(fmaxf(tot - a[15], 0.0f), 1.0f);
    // ---- asm stores: f32 alpha + bf16 copy ----
    {
      float* sb = gq + (size_t)t * SSZ;
      f32x4 v0 = {a[0], a[1], a[2], a[3]};
      f32x4 v1 = {a[4], a[5], a[6], a[7]};
      f32x4 v2 = {a[8], a[9], a[10], a[11]};
      f32x4 v3 = {a[12], a[13], a[14], a[15]};
      astore(sb + 0, v0);  astore(sb + 4, v1);
      astore(sb + 8, v2);  astore(sb + 12, v3);
      unsigned short* pbp = gpb + (size_t)t * SSZ;
      i32x4 pk0, pk1;
      pk0[0] = cvt_pk(a[0], a[1]);   pk0[1] = cvt_pk(a[2], a[3]);
      pk0[2] = cvt_pk(a[4], a[5]);   pk0[3] = cvt_pk(a[6], a[7]);
      pk1[0] = cvt_pk(a[8], a[9]);   pk1[1] = cvt_pk(a[10], a[11]);
      pk1[2] = cvt_pk(a[12], a[13]); pk1[3] = cvt_pk(a[14], a[15]);
      astore4i(pbp + 0, pk0);
      astore4i(pbp + 8, pk1);
    }
  }
}

// ---------------- K3: X = alpha_bf16 @ V^T_bf16 via MFMA -> g_Xb ----------------
__global__ __launch_bounds__(256) void k_av() {
  const int tid = threadIdx.x, w = tid >> 6, l = tid & 63;
  const int rl = l & 15, kg = l >> 4;
  const int gw = blockIdx.x * 4 + w;
  const int bh = gw >> 6;
  const int t0 = (gw & 63) << 4;

  const unsigned short* ab = g_Pb + ((size_t)bh * TT + t0 + rl) * SSZ;
  const unsigned short* vb = g_Vt + (size_t)bh * DD * SSZ;

  f32x4 acc[4];
#pragma unroll
  for (int j = 0; j < 4; ++j) acc[j] = (f32x4)0.0f;

  for (int kk = 0; kk < 32; ++kk) {
    const int kof = (kk << 5) + (kg << 3);
    s16x8 a = *(const s16x8*)(ab + kof);
#pragma unroll
    for (int fj = 0; fj < 4; ++fj) {
      s16x8 b = *(const s16x8*)(vb + (size_t)(fj * 16 + rl) * SSZ + kof);
      acc[fj] = __builtin_amdgcn_mfma_f32_16x16x32_bf16(a, b, acc[fj], 0, 0, 0);
    }
  }

  const int bz = bh >> 4, hh = bh & 15;
#pragma unroll
  for (int fj = 0; fj < 4; ++fj) {
    const int d = fj * 16 + rl;
#pragma unroll
    for (int r = 0; r < 4; ++r) {
      const int t = t0 + (kg << 2) + r;
      g_Xb[((size_t)t * BSZN + bz) * EEN + hh * DD + d] = bfr(acc[fj][r]);
    }
  }
}

// ---------------- K4: Out = X_bf16 @ W_bf16^T + b via MFMA ----------------
__global__ __launch_bounds__(256) void k_out(const float* __restrict__ Bb,
                                             float* __restrict__ Out) {
  const int tid = threadIdx.x, w = tid >> 6, l = tid & 63;
  const int rl = l & 15, kg = l >> 4;
  const int gw = blockIdx.x * 4 + w;
  const int m0 = (gw >> 4) << 4;
  const int n0 = (gw & 15) << 6;

  const unsigned short* xb = g_Xb + (size_t)(m0 + rl) * EEN;

  f32x4 acc[4];
#pragma unroll
  for (int j = 0; j < 4; ++j) acc[j] = (f32x4)0.0f;

  for (int kk = 0; kk < 32; ++kk) {
    const int kof = (kk << 5) + (kg << 3);
    s16x8 a = *(const s16x8*)(xb + kof);
#pragma unroll
    for (int fj = 0; fj < 4; ++fj) {
      s16x8 b = *(const s16x8*)(g_Wb + (size_t)(n0 + fj * 16 + rl) * EEN + kof);
      acc[fj] = __builtin_amdgcn_mfma_f32_16x16x32_bf16(a, b, acc[fj], 0, 0, 0);
    }
  }

#pragma unroll
  for (int fj = 0; fj < 4; ++fj) {
    const float bias = Bb[n0 + fj * 16 + rl];
#pragma unroll
    for (int r = 0; r < 4; ++r) {
      const int m = m0 + (kg << 2) + r;
      Out[(size_t)m * EEN + n0 + fj * 16 + rl] = acc[fj][r] + bias;
    }
  }
}

extern "C" void kernel_launch(void* const* d_in, const int* in_sizes, int n_in,
                              void* d_out, int out_size, void* d_ws, size_t ws_size,
                              hipStream_t stream) {
  const float* Q  = (const float*)d_in[0];
  const float* K  = (const float*)d_in[1];
  const float* V  = (const float*)d_in[2];
  const float* W  = (const float*)d_in[3];
  const float* Bb = (const float*)d_in[4];
  const float* eb = (const float*)d_in[5];
  float* Out = (float*)d_out;
  float* Alpha = Out + (size_t)TT * BSZN * EEN;  // output #1 region, also staging for p_choose

  k_prep_w<<<dim3(512), dim3(256), 0, stream>>>(W);
  k_prep_v<<<dim3(BHN * 16), dim3(256), 0, stream>>>(V);
  k_energy<<<dim3(BHN * 64), dim3(256), 0, stream>>>(Q, K, eb, Alpha);
  k_scan<<<dim3(BHN), dim3(64), 0, stream>>>(Alpha);
  k_av<<<dim3(1024), dim3(256), 0, stream>>>();
  k_out<<<dim3(1024), dim3(256), 0, stream>>>(Bb, Out);
}

// Round 11
// 757.088 us; speedup vs baseline: 1.2337x; 1.2337x over previous
//
#include <hip/hip_runtime.h>

#define TT 1024
#define SSZ 1024
#define DD 64
#define BHN 64
#define BSZN 4
#define EEN 1024
#define EPSF 1e-6f

using f32x4 = __attribute__((ext_vector_type(4))) float;
using i32x2 = __attribute__((ext_vector_type(2))) int;
using i32x4 = __attribute__((ext_vector_type(4))) int;
using s16x8 = __attribute__((ext_vector_type(8))) short;

// static buffers (avoid ws_size assumptions)
__device__ unsigned short g_Qb[(size_t)BHN * TT * SSZ];  // bf16 p_choose (134MB)
__device__ unsigned short g_Pb[(size_t)BHN * TT * SSZ];  // bf16 alpha copy (134MB)
__device__ unsigned short g_Vt[(size_t)BHN * DD * SSZ];  // bf16 V^T [bh][d][s] (8MB)
__device__ unsigned short g_Wb[(size_t)EEN * EEN];       // bf16 W [n][k] (2MB)
__device__ unsigned short g_Xb[(size_t)TT * BSZN * EEN]; // bf16 X [t][bz][e] (8MB)

// ---------------- helpers ----------------
template<int CTRL, int RM>
__device__ __forceinline__ float f_dpp(float x, float ident) {
  return __builtin_bit_cast(float,
      __builtin_amdgcn_update_dpp(__builtin_bit_cast(int, ident),
                                  __builtin_bit_cast(int, x),
                                  CTRL, RM, 0xF, false));
}

__device__ __forceinline__ float wscan_add(float x) {
  x += f_dpp<0x111, 0xF>(x, 0.0f);
  x += f_dpp<0x112, 0xF>(x, 0.0f);
  x += f_dpp<0x114, 0xF>(x, 0.0f);
  x += f_dpp<0x118, 0xF>(x, 0.0f);
  x += f_dpp<0x142, 0xA>(x, 0.0f);
  x += f_dpp<0x143, 0xC>(x, 0.0f);
  return x;
}

__device__ __forceinline__ float wave_shr1(float x, float ident) {
  return f_dpp<0x138, 0xF>(x, ident);
}

__device__ __forceinline__ i32x2 aload2(const unsigned short* p) {
  i32x2 r;
  asm volatile("global_load_dwordx2 %0, %1, off" : "=v"(r) : "v"(p));
  return r;
}
__device__ __forceinline__ void astore(float* p, f32x4 v) {
  asm volatile("global_store_dwordx4 %0, %1, off" :: "v"(p), "v"(v) : "memory");
}
__device__ __forceinline__ void astore2(unsigned short* p, i32x2 v) {
  asm volatile("global_store_dwordx2 %0, %1, off" :: "v"(p), "v"(v) : "memory");
}

__device__ __forceinline__ int cvt_pk(float lo, float hi) {
  int r;
  asm("v_cvt_pk_bf16_f32 %0, %1, %2" : "=v"(r) : "v"(lo), "v"(hi));
  return r;
}
__device__ __forceinline__ unsigned short bfr(float x) {  // scalar RTNE bf16
  unsigned u = __builtin_bit_cast(unsigned, x);
  u += 0x7fffu + ((u >> 16) & 1u);
  return (unsigned short)(u >> 16);
}
__device__ __forceinline__ float bfl(int u) {  // low bf16 -> f32
  return __builtin_bit_cast(float, u << 16);
}
__device__ __forceinline__ float bfh(int u) {  // high bf16 -> f32
  return __builtin_bit_cast(float, (int)((unsigned)u & 0xffff0000u));
}
__device__ __forceinline__ s16x8 pack8p(const float* p) {  // 8 consecutive f32 -> bf16x8
  f32x4 a = *(const f32x4*)p;
  f32x4 b = *(const f32x4*)(p + 4);
  i32x4 r;
  r[0] = cvt_pk(a[0], a[1]); r[1] = cvt_pk(a[2], a[3]);
  r[2] = cvt_pk(b[0], b[1]); r[3] = cvt_pk(b[2], b[3]);
  return __builtin_bit_cast(s16x8, r);
}
__device__ __forceinline__ s16x8 pack8f(float v0, float v1, float v2, float v3,
                                        float v4, float v5, float v6, float v7) {
  i32x4 r;
  r[0] = cvt_pk(v0, v1); r[1] = cvt_pk(v2, v3);
  r[2] = cvt_pk(v4, v5); r[3] = cvt_pk(v6, v7);
  return __builtin_bit_cast(s16x8, r);
}

// ---------------- prep: W -> bf16 ----------------
__global__ __launch_bounds__(256) void k_prep_w(const float* __restrict__ W) {
  const size_t idx = ((size_t)blockIdx.x * 256 + threadIdx.x) * 8;
  *(s16x8*)(g_Wb + idx) = pack8p(W + idx);
}

// ---------------- prep: V -> bf16 transposed V^T[bh][d][s] ----------------
__global__ __launch_bounds__(256) void k_prep_v(const float* __restrict__ V) {
  __shared__ float tile[64][65];
  const int tid = threadIdx.x;
  const int bh = blockIdx.x >> 4;
  const int s0 = (blockIdx.x & 15) << 6;
  {
    const int r = tid >> 2, cq = (tid & 3) << 4;
    const float* src = V + ((size_t)bh * SSZ + s0 + r) * DD + cq;
    *(float4*)&tile[r][cq + 0]  = *(const float4*)(src + 0);
    *(float4*)&tile[r][cq + 4]  = *(const float4*)(src + 4);
    *(float4*)&tile[r][cq + 8]  = *(const float4*)(src + 8);
    *(float4*)&tile[r][cq + 12] = *(const float4*)(src + 12);
  }
  __syncthreads();
  {
    const int d = tid >> 2, sq = (tid & 3) << 4;
    unsigned short* dst = g_Vt + ((size_t)bh * DD + d) * SSZ + s0 + sq;
    *(s16x8*)(dst + 0) = pack8f(tile[sq + 0][d], tile[sq + 1][d], tile[sq + 2][d], tile[sq + 3][d],
                                tile[sq + 4][d], tile[sq + 5][d], tile[sq + 6][d], tile[sq + 7][d]);
    *(s16x8*)(dst + 8) = pack8f(tile[sq + 8][d], tile[sq + 9][d], tile[sq + 10][d], tile[sq + 11][d],
                                tile[sq + 12][d], tile[sq + 13][d], tile[sq + 14][d], tile[sq + 15][d]);
  }
}

// ---------------- K1: p = sigmoid(Q K^T + bias) via bf16 MFMA -> g_Qb (bf16) ----------------
__global__ __launch_bounds__(256) void k_energy(const float* __restrict__ Q,
                                                const float* __restrict__ Kp,
                                                const float* __restrict__ eb) {
  const int tid = threadIdx.x, w = tid >> 6, l = tid & 63;
  const int rl = l & 15, kg = l >> 4;
  const int bh = blockIdx.x >> 6;
  const int tile = blockIdx.x & 63;
  const int m0 = (tile >> 2) << 6;
  const int n0 = (((tile & 3) << 2) + w) << 6;
  const float* qb = Q + (size_t)bh * TT * DD;
  const float* kb = Kp + (size_t)bh * SSZ * DD;

  f32x4 acc[4][4];
#pragma unroll
  for (int i = 0; i < 4; ++i)
#pragma unroll
    for (int j = 0; j < 4; ++j) acc[i][j] = (f32x4)0.0f;

#pragma unroll
  for (int ks = 0; ks < 2; ++ks) {
    const int kof = (ks << 5) + (kg << 3);
    s16x8 af[4], bf[4];
#pragma unroll
    for (int fi = 0; fi < 4; ++fi)
      af[fi] = pack8p(qb + (size_t)(m0 + fi * 16 + rl) * DD + kof);
#pragma unroll
    for (int fj = 0; fj < 4; ++fj)
      bf[fj] = pack8p(kb + (size_t)(n0 + fj * 16 + rl) * DD + kof);
#pragma unroll
    for (int fi = 0; fi < 4; ++fi)
#pragma unroll
      for (int fj = 0; fj < 4; ++fj)
        acc[fi][fj] = __builtin_amdgcn_mfma_f32_16x16x32_bf16(af[fi], bf[fj], acc[fi][fj], 0, 0, 0);
  }

  const float bias = eb[0];
  unsigned short* pb = g_Qb + (size_t)bh * TT * SSZ;
#pragma unroll
  for (int fi = 0; fi < 4; ++fi)
#pragma unroll
    for (int r = 0; r < 4; ++r) {
      const size_t rowoff = (size_t)(m0 + fi * 16 + (kg << 2) + r) * SSZ;
#pragma unroll
      for (int fj = 0; fj < 4; ++fj) {
        float x = acc[fi][fj][r] + bias;
        float s = __builtin_amdgcn_rcpf(1.0f + __expf(-x));
        pb[rowoff + n0 + fj * 16 + rl] = bfr(s);
      }
    }
}

// ---------------- K2: 4-wave s-split scan (round-6 proven structure), bf16 p loads ----------------
#define STEP(T, QS) do {                                                       \
  const int t_ = (T);                                                          \
  asm volatile("s_waitcnt vmcnt(8)" ::: "memory");                             \
  __builtin_amdgcn_sched_barrier(0);                                           \
  float fn0 = 1.0f - bfl(QS[0]);                                               \
  float fn1 = 1.0f - bfh(QS[0]);                                               \
  float fn2 = 1.0f - bfl(QS[1]);                                               \
  float fn3 = 1.0f - bfh(QS[1]);                                               \
  { int rr = t_ + 5; if (rr > TT - 1) rr = TT - 1;                             \
    QS = aload2(gqe + (size_t)rr * SSZ); }                                     \
  float ln0 = fn0, ln1 = ln0 * fn1, ln2 = ln1 * fn2, ln3 = ln2 * fn3;          \
  float An0 = ln3;                                                             \
  float An1 = An0 * f_dpp<0x111, 0xF>(An0, 1.0f);                              \
  float An2 = An1 * f_dpp<0x112, 0xF>(An1, 1.0f);                              \
  float An3 = An2 * f_dpp<0x114, 0xF>(An2, 1.0f);                              \
  float An4 = An3 * f_dpp<0x118, 0xF>(An3, 1.0f);                              \
  float An5 = An4 * f_dpp<0x142, 0xA>(An4, 1.0f);                              \
  float An6 = An5 * f_dpp<0x143, 0xC>(An5, 1.0f);                              \
  float wEn = wave_shr1(An6, 1.0f);                                            \
  float bb0 = fminf(c0  * prev0, prev0);                                       \
  float bb1 = fminf(cl0 * prev1, prev1);                                       \
  float bb2 = fminf(cl1 * prev2, prev2);                                       \
  float bb3 = fminf(cl2 * prev3, prev3);                                       \
  float Blo1 = fmaf(fc0, bb0, bb1);                                            \
  float Blo2 = fmaf(fc1, Blo1, bb2);                                           \
  float Blo3 = fmaf(fc2, Blo2, bb3);                                           \
  float B_ = fc3 * Blo3;                                                       \
  B_ = fmaf(As0, f_dpp<0x111, 0xF>(B_, 0.0f), B_);                             \
  B_ = fmaf(As1, f_dpp<0x112, 0xF>(B_, 0.0f), B_);                             \
  B_ = fmaf(As2, f_dpp<0x114, 0xF>(B_, 0.0f), B_);                             \
  B_ = fmaf(As3, f_dpp<0x118, 0xF>(B_, 0.0f), B_);                             \
  B_ = fmaf(As4, f_dpp<0x142, 0xA>(B_, 0.0f), B_);                             \
  float Bfull = fmaf(As5, f_dpp<0x143, 0xC>(B_, 0.0f), B_);                    \
  float wB = wave_shr1(Bfull, 0.0f);                                           \
  if (lane == 63) ldsAB[t_ & 1][w] = make_float2(An6, Bfull);                  \
  asm volatile("s_waitcnt lgkmcnt(0)" ::: "memory");                           \
  __builtin_amdgcn_s_barrier();                                                \
  __builtin_amdgcn_sched_barrier(0);                                           \
  float2 ab0 = ldsAB[t_ & 1][0];                                               \
  float2 ab1 = ldsAB[t_ & 1][1];                                               \
  float2 ab2 = ldsAB[t_ & 1][2];                                               \
  float Ew = 0.0f;                                                             \
  if (w == 1) Ew = ab0.y;                                                      \
  else if (w == 2) Ew = fmaf(A1g, ab0.y, ab1.y);                               \
  else if (w == 3) Ew = fmaf(A2g, fmaf(A1g, ab0.y, ab1.y), ab2.y);             \
  float El = fmaf(wE, Ew, wB);                                                 \
  float D0 = bb0 + El;                                                         \
  float D1 = fmaf(lc0, El, Blo1);                                              \
  float D2 = fmaf(lc1, El, Blo2);                                              \
  float D3 = fmaf(lc2, El, Blo3);                                              \
  float a0 = fminf(fmaf(-fc0, D0, D0), 1.0f);                                  \
  float a1 = fminf(fmaf(-fc1, D1, D1), 1.0f);                                  \
  float a2 = fminf(fmaf(-fc2, D2, D2), 1.0f);                                  \
  float a3 = fminf(fmaf(-fc3, D3, D3), 1.0f);                                  \
  prev0 = a0; prev1 = a1; prev2 = a2; prev3 = a3;                              \
  f32x4 av4; av4.x = a0; av4.y = a1; av4.z = a2; av4.w = a3;                   \
  if (tid != 255) {                                                            \
    astore(gq + (size_t)t_ * SSZ, av4);                                        \
    i32x2 pk; pk[0] = cvt_pk(a0, a1); pk[1] = cvt_pk(a2, a3);                  \
    astore2(gpb + (size_t)t_ * SSZ, pk);                                       \
  }                                                                            \
  float la = (a0 + a1) + (a2 + a3);                                            \
  float wsum = wscan_add(la);                                                  \
  if (lane == 63 && w < 3) ldsS[t_ & 1][w] = wsum;                             \
  if (tid == 255) {                                                            \
    if (t_ > 0) {                                                              \
      float tot = ldsS[(t_ - 1) & 1][0] + ldsS[(t_ - 1) & 1][1]                \
                + ldsS[(t_ - 1) & 1][2] + wsum_prev;                           \
      float rest = tot - pend.w;                                               \
      pend.w = 1.0f - fminf(fmaxf(rest, 0.0f), 1.0f);                          \
      astore(gq + (size_t)(t_ - 1) * SSZ, pend);                               \
      i32x2 pk2; pk2[0] = cvt_pk(pend.x, pend.y); pk2[1] = cvt_pk(pend.z, pend.w); \
      astore2(gpb + (size_t)(t_ - 1) * SSZ, pk2);                              \
    }                                                                          \
    pend = av4; wsum_prev = wsum;                                              \
  }                                                                            \
  fc0 = fn0; fc1 = fn1; fc2 = fn2; fc3 = fn3;                                  \
  lc0 = ln0; lc1 = ln1; lc2 = ln2;                                             \
  As0 = An0; As1 = An1; As2 = An2; As3 = An3; As4 = An4; As5 = An5;            \
  wE = wEn;                                                                    \
  float Pw_ = 1.0f;                                                            \
  if (w > 0) Pw_ = ab0.x;                                                      \
  if (w > 1) Pw_ *= ab1.x;                                                     \
  if (w > 2) Pw_ *= ab2.x;                                                     \
  c0 = (Pw_ * 1e6f) * wEn;                                                     \
  cl0 = c0 * ln0; cl1 = c0 * ln1; cl2 = c0 * ln2;                              \
  A1g = ab1.x; A2g = ab2.x;                                                    \
} while (0)

__global__ __launch_bounds__(256, 1) void k_scan(float* __restrict__ A) {
  const int b = blockIdx.x;
  const int tid = threadIdx.x;
  const int w = tid >> 6;
  const int lane = tid & 63;
  __shared__ float2 ldsAB[2][4];
  __shared__ float ldsS[2][4];

  float* gq = A + (size_t)b * TT * SSZ + ((size_t)w << 8) + ((size_t)lane << 2);
  const unsigned short* gqe = g_Qb + (size_t)b * TT * SSZ + ((size_t)w << 8) + ((size_t)lane << 2);
  unsigned short* gpb = g_Pb + (size_t)b * TT * SSZ + ((size_t)w << 8) + ((size_t)lane << 2);

  // ring: slot k holds row r with r&3==k
  i32x2 q0 = aload2(gqe + (size_t)0 * SSZ);
  i32x2 q1 = aload2(gqe + (size_t)1 * SSZ);
  i32x2 q2 = aload2(gqe + (size_t)2 * SSZ);
  i32x2 q3 = aload2(gqe + (size_t)3 * SSZ);
  asm volatile("s_waitcnt vmcnt(0)" ::: "memory");
  __builtin_amdgcn_sched_barrier(0);

  // row-0 state
  float fc0 = 1.0f - bfl(q0[0]);
  float fc1 = 1.0f - bfh(q0[0]);
  float fc2 = 1.0f - bfl(q0[1]);
  float fc3 = 1.0f - bfh(q0[1]);
  q0 = aload2(gqe + (size_t)4 * SSZ);
  float lc0 = fc0, lc1 = lc0 * fc1, lc2 = lc1 * fc2;
  float lc3 = lc2 * fc3;
  float As0 = lc3;
  float As1 = As0 * f_dpp<0x111, 0xF>(As0, 1.0f);
  float As2 = As1 * f_dpp<0x112, 0xF>(As1, 1.0f);
  float As3 = As2 * f_dpp<0x114, 0xF>(As2, 1.0f);
  float As4 = As3 * f_dpp<0x118, 0xF>(As3, 1.0f);
  float As5 = As4 * f_dpp<0x142, 0xA>(As4, 1.0f);
  float A6  = As5 * f_dpp<0x143, 0xC>(As5, 1.0f);
  float wE = wave_shr1(A6, 1.0f);
  if (lane == 63) ldsAB[1][w] = make_float2(A6, 0.0f);
  asm volatile("s_waitcnt lgkmcnt(0)" ::: "memory");
  __builtin_amdgcn_s_barrier();
  __builtin_amdgcn_sched_barrier(0);
  float2 pab0 = ldsAB[1][0], pab1 = ldsAB[1][1], pab2 = ldsAB[1][2];
  float A1g = pab1.x, A2g = pab2.x;
  float Pw = 1.0f;
  if (w > 0) Pw = pab0.x;
  if (w > 1) Pw *= pab1.x;
  if (w > 2) Pw *= pab2.x;
  float c0 = (Pw * 1e6f) * wE;
  float cl0 = c0 * lc0, cl1 = c0 * lc1, cl2 = c0 * lc2;

  float prev0 = (tid == 0) ? 1.0f : 0.0f;
  float prev1 = 0.0f, prev2 = 0.0f, prev3 = 0.0f;
  f32x4 pend; pend.x = 0.0f; pend.y = 0.0f; pend.z = 0.0f; pend.w = 0.0f;
  float wsum_prev = 0.0f;

  for (int t0 = 0; t0 < TT; t0 += 4) {
    STEP(t0 + 0, q1);
    STEP(t0 + 1, q2);
    STEP(t0 + 2, q3);
    STEP(t0 + 3, q0);
  }

  asm volatile("s_waitcnt lgkmcnt(0)" ::: "memory");
  __builtin_amdgcn_s_barrier();
  __builtin_amdgcn_sched_barrier(0);
  if (tid == 255) {
    float tot = ldsS[(TT - 1) & 1][0] + ldsS[(TT - 1) & 1][1]
              + ldsS[(TT - 1) & 1][2] + wsum_prev;
    float rest = tot - pend.w;
    pend.w = 1.0f - fminf(fmaxf(rest, 0.0f), 1.0f);
    astore(gq + (size_t)(TT - 1) * SSZ, pend);
    i32x2 pk; pk[0] = cvt_pk(pend.x, pend.y); pk[1] = cvt_pk(pend.z, pend.w);
    astore2(gpb + (size_t)(TT - 1) * SSZ, pk);
  }
}

// ---------------- K3: X = alpha_bf16 @ V^T_bf16 via MFMA -> g_Xb ----------------
__global__ __launch_bounds__(256) void k_av() {
  const int tid = threadIdx.x, w = tid >> 6, l = tid & 63;
  const int rl = l & 15, kg = l >> 4;
  const int gw = blockIdx.x * 4 + w;
  const int bh = gw >> 6;
  const int t0 = (gw & 63) << 4;

  const unsigned short* ab = g_Pb + ((size_t)bh * TT + t0 + rl) * SSZ;
  const unsigned short* vb = g_Vt + (size_t)bh * DD * SSZ;

  f32x4 acc[4];
#pragma unroll
  for (int j = 0; j < 4; ++j) acc[j] = (f32x4)0.0f;

  for (int kk = 0; kk < 32; ++kk) {
    const int kof = (kk << 5) + (kg << 3);
    s16x8 a = *(const s16x8*)(ab + kof);
#pragma unroll
    for (int fj = 0; fj < 4; ++fj) {
      s16x8 b = *(const s16x8*)(vb + (size_t)(fj * 16 + rl) * SSZ + kof);
      acc[fj] = __builtin_amdgcn_mfma_f32_16x16x32_bf16(a, b, acc[fj], 0, 0, 0);
    }
  }

  const int bz = bh >> 4, hh = bh & 15;
#pragma unroll
  for (int fj = 0; fj < 4; ++fj) {
    const int d = fj * 16 + rl;
#pragma unroll
    for (int r = 0; r < 4; ++r) {
      const int t = t0 + (kg << 2) + r;
      g_Xb[((size_t)t * BSZN + bz) * EEN + hh * DD + d] = bfr(acc[fj][r]);
    }
  }
}

// ---------------- K4: Out = X_bf16 @ W_bf16^T + b via MFMA ----------------
__global__ __launch_bounds__(256) void k_out(const float* __restrict__ Bb,
                                             float* __restrict__ Out) {
  const int tid = threadIdx.x, w = tid >> 6, l = tid & 63;
  const int rl = l & 15, kg = l >> 4;
  const int gw = blockIdx.x * 4 + w;
  const int m0 = (gw >> 4) << 4;
  const int n0 = (gw & 15) << 6;

  const unsigned short* xb = g_Xb + (size_t)(m0 + rl) * EEN;

  f32x4 acc[4];
#pragma unroll
  for (int j = 0; j < 4; ++j) acc[j] = (f32x4)0.0f;

  for (int kk = 0; kk < 32; ++kk) {
    const int kof = (kk << 5) + (kg << 3);
    s16x8 a = *(const s16x8*)(xb + kof);
#pragma unroll
    for (int fj = 0; fj < 4; ++fj) {
      s16x8 b = *(const s16x8*)(g_Wb + (size_t)(n0 + fj * 16 + rl) * EEN + kof);
      acc[fj] = __builtin_amdgcn_mfma_f32_16x16x32_bf16(a, b, acc[fj], 0, 0, 0);
    }
  }

#pragma unroll
  for (int fj = 0; fj < 4; ++fj) {
    const float bias = Bb[n0 + fj * 16 + rl];
#pragma unroll
    for (int r = 0; r < 4; ++r) {
      const int m = m0 + (kg << 2) + r;
      Out[(size_t)m * EEN + n0 + fj * 16 + rl] = acc[fj][r] + bias;
    }
  }
}

extern "C" void kernel_launch(void* const* d_in, const int* in_sizes, int n_in,
                              void* d_out, int out_size, void* d_ws, size_t ws_size,
                              hipStream_t stream) {
  const float* Q  = (const float*)d_in[0];
  const float* K  = (const float*)d_in[1];
  const float* V  = (const float*)d_in[2];
  const float* W  = (const float*)d_in[3];
  const float* Bb = (const float*)d_in[4];
  const float* eb = (const float*)d_in[5];
  float* Out = (float*)d_out;
  float* Alpha = Out + (size_t)TT * BSZN * EEN;  // alpha f32 output region (pure output now)

  k_prep_w<<<dim3(512), dim3(256), 0, stream>>>(W);
  k_prep_v<<<dim3(BHN * 16), dim3(256), 0, stream>>>(V);
  k_energy<<<dim3(BHN * 64), dim3(256), 0, stream>>>(Q, K, eb);
  k_scan<<<dim3(BHN), dim3(256), 0, stream>>>(Alpha);
  k_av<<<dim3(1024), dim3(256), 0, stream>>>();
  k_out<<<dim3(1024), dim3(256), 0, stream>>>(Bb, Out);
}

// Round 13
// 751.914 us; speedup vs baseline: 1.2422x; 1.0069x over previous
//
#include <hip/hip_runtime.h>

#define TT 1024
#define SSZ 1024
#define DD 64
#define BHN 64
#define BSZN 4
#define EEN 1024
#define EPSF 1e-6f

using f32x4 = __attribute__((ext_vector_type(4))) float;
using i32x2 = __attribute__((ext_vector_type(2))) int;
using i32x4 = __attribute__((ext_vector_type(4))) int;
using s16x8 = __attribute__((ext_vector_type(8))) short;

// static buffers (avoid ws_size assumptions)
__device__ unsigned short g_Qb[(size_t)BHN * TT * SSZ];  // bf16 p_choose, row-major [bh][t][s]
__device__ unsigned short g_Pb[(size_t)BHN * TT * SSZ];  // bf16 alpha, k-blocked [bh*32+sb][t][32]
__device__ unsigned short g_Vt[(size_t)BHN * DD * SSZ];  // bf16 V^T row-major [bh][d][s]
__device__ unsigned short g_Wb[(size_t)EEN * EEN];       // bf16 W row-major [n][k]
__device__ unsigned short g_Xb[(size_t)TT * BSZN * EEN]; // bf16 X row-major [t][bz][e]

// ---------------- helpers ----------------
template<int CTRL, int RM>
__device__ __forceinline__ float f_dpp(float x, float ident) {
  return __builtin_bit_cast(float,
      __builtin_amdgcn_update_dpp(__builtin_bit_cast(int, ident),
                                  __builtin_bit_cast(int, x),
                                  CTRL, RM, 0xF, false));
}

__device__ __forceinline__ float wscan_add(float x) {
  x += f_dpp<0x111, 0xF>(x, 0.0f);
  x += f_dpp<0x112, 0xF>(x, 0.0f);
  x += f_dpp<0x114, 0xF>(x, 0.0f);
  x += f_dpp<0x118, 0xF>(x, 0.0f);
  x += f_dpp<0x142, 0xA>(x, 0.0f);
  x += f_dpp<0x143, 0xC>(x, 0.0f);
  return x;
}

__device__ __forceinline__ float wave_shr1(float x, float ident) {
  return f_dpp<0x138, 0xF>(x, ident);
}

__device__ __forceinline__ i32x2 aload2(const unsigned short* p) {
  i32x2 r;
  asm volatile("global_load_dwordx2 %0, %1, off" : "=v"(r) : "v"(p));
  return r;
}
__device__ __forceinline__ void astore(float* p, f32x4 v) {
  asm volatile("global_store_dwordx4 %0, %1, off" :: "v"(p), "v"(v) : "memory");
}
__device__ __forceinline__ void astore2(unsigned short* p, i32x2 v) {
  asm volatile("global_store_dwordx2 %0, %1, off" :: "v"(p), "v"(v) : "memory");
}

__device__ __forceinline__ int cvt_pk(float lo, float hi) {
  int r;
  asm("v_cvt_pk_bf16_f32 %0, %1, %2" : "=v"(r) : "v"(lo), "v"(hi));
  return r;
}
__device__ __forceinline__ unsigned short bfr(float x) {  // scalar RTNE bf16
  unsigned u = __builtin_bit_cast(unsigned, x);
  u += 0x7fffu + ((u >> 16) & 1u);
  return (unsigned short)(u >> 16);
}
__device__ __forceinline__ float bfl(int u) {  // low bf16 -> f32
  return __builtin_bit_cast(float, u << 16);
}
__device__ __forceinline__ float bfh(int u) {  // high bf16 -> f32
  return __builtin_bit_cast(float, (int)((unsigned)u & 0xffff0000u));
}
__device__ __forceinline__ s16x8 pack8p(const float* p) {  // 8 consecutive f32 -> bf16x8
  f32x4 a = *(const f32x4*)p;
  f32x4 b = *(const f32x4*)(p + 4);
  i32x4 r;
  r[0] = cvt_pk(a[0], a[1]); r[1] = cvt_pk(a[2], a[3]);
  r[2] = cvt_pk(b[0], b[1]); r[3] = cvt_pk(b[2], b[3]);
  return __builtin_bit_cast(s16x8, r);
}
__device__ __forceinline__ s16x8 pack8f(float v0, float v1, float v2, float v3,
                                        float v4, float v5, float v6, float v7) {
  i32x4 r;
  r[0] = cvt_pk(v0, v1); r[1] = cvt_pk(v2, v3);
  r[2] = cvt_pk(v4, v5); r[3] = cvt_pk(v6, v7);
  return __builtin_bit_cast(s16x8, r);
}

// ---------------- prep: W -> bf16 ----------------
__global__ __launch_bounds__(256) void k_prep_w(const float* __restrict__ W) {
  const size_t idx = ((size_t)blockIdx.x * 256 + threadIdx.x) * 8;
  *(s16x8*)(g_Wb + idx) = pack8p(W + idx);
}

// ---------------- prep: V -> bf16 transposed V^T[bh][d][s] ----------------
__global__ __launch_bounds__(256) void k_prep_v(const float* __restrict__ V) {
  __shared__ float tile[64][65];
  const int tid = threadIdx.x;
  const int bh = blockIdx.x >> 4;
  const int s0 = (blockIdx.x & 15) << 6;
  {
    const int r = tid >> 2, cq = (tid & 3) << 4;
    const float* src = V + ((size_t)bh * SSZ + s0 + r) * DD + cq;
    *(float4*)&tile[r][cq + 0]  = *(const float4*)(src + 0);
    *(float4*)&tile[r][cq + 4]  = *(const float4*)(src + 4);
    *(float4*)&tile[r][cq + 8]  = *(const float4*)(src + 8);
    *(float4*)&tile[r][cq + 12] = *(const float4*)(src + 12);
  }
  __syncthreads();
  {
    const int d = tid >> 2, sq = (tid & 3) << 4;
    unsigned short* dst = g_Vt + ((size_t)bh * DD + d) * SSZ + s0 + sq;
    *(s16x8*)(dst + 0) = pack8f(tile[sq + 0][d], tile[sq + 1][d], tile[sq + 2][d], tile[sq + 3][d],
                                tile[sq + 4][d], tile[sq + 5][d], tile[sq + 6][d], tile[sq + 7][d]);
    *(s16x8*)(dst + 8) = pack8f(tile[sq + 8][d], tile[sq + 9][d], tile[sq + 10][d], tile[sq + 11][d],
                                tile[sq + 12][d], tile[sq + 13][d], tile[sq + 14][d], tile[sq + 15][d]);
  }
}

// ---------------- K1: p = sigmoid(Q K^T + bias) via bf16 MFMA -> g_Qb (bf16) ----------------
__global__ __launch_bounds__(256) void k_energy(const float* __restrict__ Q,
                                                const float* __restrict__ Kp,
                                                const float* __restrict__ eb) {
  const int tid = threadIdx.x, w = tid >> 6, l = tid & 63;
  const int rl = l & 15, kg = l >> 4;
  const int bh = blockIdx.x >> 6;
  const int tile = blockIdx.x & 63;
  const int m0 = (tile >> 2) << 6;
  const int n0 = (((tile & 3) << 2) + w) << 6;
  const float* qb = Q + (size_t)bh * TT * DD;
  const float* kb = Kp + (size_t)bh * SSZ * DD;

  f32x4 acc[4][4];
#pragma unroll
  for (int i = 0; i < 4; ++i)
#pragma unroll
    for (int j = 0; j < 4; ++j) acc[i][j] = (f32x4)0.0f;

#pragma unroll
  for (int ks = 0; ks < 2; ++ks) {
    const int kof = (ks << 5) + (kg << 3);
    s16x8 af[4], bf[4];
#pragma unroll
    for (int fi = 0; fi < 4; ++fi)
      af[fi] = pack8p(qb + (size_t)(m0 + fi * 16 + rl) * DD + kof);
#pragma unroll
    for (int fj = 0; fj < 4; ++fj)
      bf[fj] = pack8p(kb + (size_t)(n0 + fj * 16 + rl) * DD + kof);
#pragma unroll
    for (int fi = 0; fi < 4; ++fi)
#pragma unroll
      for (int fj = 0; fj < 4; ++fj)
        acc[fi][fj] = __builtin_amdgcn_mfma_f32_16x16x32_bf16(af[fi], bf[fj], acc[fi][fj], 0, 0, 0);
  }

  const float bias = eb[0];
  unsigned short* pb = g_Qb + (size_t)bh * TT * SSZ;
#pragma unroll
  for (int fi = 0; fi < 4; ++fi)
#pragma unroll
    for (int r = 0; r < 4; ++r) {
      const size_t rowoff = (size_t)(m0 + fi * 16 + (kg << 2) + r) * SSZ;
#pragma unroll
      for (int fj = 0; fj < 4; ++fj) {
        float x = acc[fi][fj][r] + bias;
        float s = __builtin_amdgcn_rcpf(1.0f + __expf(-x));
        pb[rowoff + n0 + fj * 16 + rl] = bfr(s);
      }
    }
}

// ---------------- K2: 4-wave s-split scan (proven structure); g_Pb write k-blocked ----------------
#define STEP(T, QS) do {                                                       \
  const int t_ = (T);                                                          \
  asm volatile("s_waitcnt vmcnt(8)" ::: "memory");                             \
  __builtin_amdgcn_sched_barrier(0);                                           \
  float fn0 = 1.0f - bfl(QS[0]);                                               \
  float fn1 = 1.0f - bfh(QS[0]);                                               \
  float fn2 = 1.0f - bfl(QS[1]);                                               \
  float fn3 = 1.0f - bfh(QS[1]);                                               \
  { int rr = t_ + 5; if (rr > TT - 1) rr = TT - 1;                             \
    QS = aload2(gqe + (size_t)rr * SSZ); }                                     \
  float ln0 = fn0, ln1 = ln0 * fn1, ln2 = ln1 * fn2, ln3 = ln2 * fn3;          \
  float An0 = ln3;                                                             \
  float An1 = An0 * f_dpp<0x111, 0xF>(An0, 1.0f);                              \
  float An2 = An1 * f_dpp<0x112, 0xF>(An1, 1.0f);                              \
  float An3 = An2 * f_dpp<0x114, 0xF>(An2, 1.0f);                              \
  float An4 = An3 * f_dpp<0x118, 0xF>(An3, 1.0f);                              \
  float An5 = An4 * f_dpp<0x142, 0xA>(An4, 1.0f);                              \
  float An6 = An5 * f_dpp<0x143, 0xC>(An5, 1.0f);                              \
  float wEn = wave_shr1(An6, 1.0f);                                            \
  float bb0 = fminf(c0  * prev0, prev0);                                       \
  float bb1 = fminf(cl0 * prev1, prev1);                                       \
  float bb2 = fminf(cl1 * prev2, prev2);                                       \
  float bb3 = fminf(cl2 * prev3, prev3);                                       \
  float Blo1 = fmaf(fc0, bb0, bb1);                                            \
  float Blo2 = fmaf(fc1, Blo1, bb2);                                           \
  float Blo3 = fmaf(fc2, Blo2, bb3);                                           \
  float B_ = fc3 * Blo3;                                                       \
  B_ = fmaf(As0, f_dpp<0x111, 0xF>(B_, 0.0f), B_);                             \
  B_ = fmaf(As1, f_dpp<0x112, 0xF>(B_, 0.0f), B_);                             \
  B_ = fmaf(As2, f_dpp<0x114, 0xF>(B_, 0.0f), B_);                             \
  B_ = fmaf(As3, f_dpp<0x118, 0xF>(B_, 0.0f), B_);                             \
  B_ = fmaf(As4, f_dpp<0x142, 0xA>(B_, 0.0f), B_);                             \
  float Bfull = fmaf(As5, f_dpp<0x143, 0xC>(B_, 0.0f), B_);                    \
  float wB = wave_shr1(Bfull, 0.0f);                                           \
  if (lane == 63) ldsAB[t_ & 1][w] = make_float2(An6, Bfull);                  \
  asm volatile("s_waitcnt lgkmcnt(0)" ::: "memory");                           \
  __builtin_amdgcn_s_barrier();                                                \
  __builtin_amdgcn_sched_barrier(0);                                           \
  float2 ab0 = ldsAB[t_ & 1][0];                                               \
  float2 ab1 = ldsAB[t_ & 1][1];                                               \
  float2 ab2 = ldsAB[t_ & 1][2];                                               \
  float Ew = 0.0f;                                                             \
  if (w == 1) Ew = ab0.y;                                                      \
  else if (w == 2) Ew = fmaf(A1g, ab0.y, ab1.y);                               \
  else if (w == 3) Ew = fmaf(A2g, fmaf(A1g, ab0.y, ab1.y), ab2.y);             \
  float El = fmaf(wE, Ew, wB);                                                 \
  float D0 = bb0 + El;                                                         \
  float D1 = fmaf(lc0, El, Blo1);                                              \
  float D2 = fmaf(lc1, El, Blo2);                                              \
  float D3 = fmaf(lc2, El, Blo3);                                              \
  float a0 = fminf(fmaf(-fc0, D0, D0), 1.0f);                                  \
  float a1 = fminf(fmaf(-fc1, D1, D1), 1.0f);                                  \
  float a2 = fminf(fmaf(-fc2, D2, D2), 1.0f);                                  \
  float a3 = fminf(fmaf(-fc3, D3, D3), 1.0f);                                  \
  prev0 = a0; prev1 = a1; prev2 = a2; prev3 = a3;                              \
  f32x4 av4; av4.x = a0; av4.y = a1; av4.z = a2; av4.w = a3;                   \
  if (tid != 255) {                                                            \
    astore(gq + (size_t)t_ * SSZ, av4);                                        \
    i32x2 pk; pk[0] = cvt_pk(a0, a1); pk[1] = cvt_pk(a2, a3);                  \
    astore2(gpb + (size_t)t_ * 32, pk);                                        \
  }                                                                            \
  float la = (a0 + a1) + (a2 + a3);                                            \
  float wsum = wscan_add(la);                                                  \
  if (lane == 63 && w < 3) ldsS[t_ & 1][w] = wsum;                             \
  if (tid == 255) {                                                            \
    if (t_ > 0) {                                                              \
      float tot = ldsS[(t_ - 1) & 1][0] + ldsS[(t_ - 1) & 1][1]                \
                + ldsS[(t_ - 1) & 1][2] + wsum_prev;                           \
      float rest = tot - pend.w;                                               \
      pend.w = 1.0f - fminf(fmaxf(rest, 0.0f), 1.0f);                          \
      astore(gq + (size_t)(t_ - 1) * SSZ, pend);                               \
      i32x2 pk2; pk2[0] = cvt_pk(pend.x, pend.y); pk2[1] = cvt_pk(pend.z, pend.w); \
      astore2(gpb + (size_t)(t_ - 1) * 32, pk2);                               \
    }                                                                          \
    pend = av4; wsum_prev = wsum;                                              \
  }                                                                            \
  fc0 = fn0; fc1 = fn1; fc2 = fn2; fc3 = fn3;                                  \
  lc0 = ln0; lc1 = ln1; lc2 = ln2;                                             \
  As0 = An0; As1 = An1; As2 = An2; As3 = An3; As4 = An4; As5 = An5;            \
  wE = wEn;                                                                    \
  float Pw_ = 1.0f;                                                            \
  if (w > 0) Pw_ = ab0.x;                                                      \
  if (w > 1) Pw_ *= ab1.x;                                                     \
  if (w > 2) Pw_ *= ab2.x;                                                     \
  c0 = (Pw_ * 1e6f) * wEn;                                                     \
  cl0 = c0 * ln0; cl1 = c0 * ln1; cl2 = c0 * ln2;                              \
  A1g = ab1.x; A2g = ab2.x;                                                    \
} while (0)

__global__ __launch_bounds__(256, 1) void k_scan(float* __restrict__ A) {
  const int b = blockIdx.x;
  const int tid = threadIdx.x;
  const int w = tid >> 6;
  const int lane = tid & 63;
  __shared__ float2 ldsAB[2][4];
  __shared__ float ldsS[2][4];

  float* gq = A + (size_t)b * TT * SSZ + ((size_t)w << 8) + ((size_t)lane << 2);
  const unsigned short* gqe = g_Qb + (size_t)b * TT * SSZ + ((size_t)w << 8) + ((size_t)lane << 2);
  // k-blocked alpha-bf16 target: s = w*256 + lane*4 -> sb = s>>5, si = s&31
  const int sb = (w << 3) + (lane >> 3);
  unsigned short* gpb = g_Pb + ((size_t)(b * 32 + sb) * TT) * 32 + ((lane & 7) << 2);

  // ring: slot k holds row r with r&3==k
  i32x2 q0 = aload2(gqe + (size_t)0 * SSZ);
  i32x2 q1 = aload2(gqe + (size_t)1 * SSZ);
  i32x2 q2 = aload2(gqe + (size_t)2 * SSZ);
  i32x2 q3 = aload2(gqe + (size_t)3 * SSZ);
  asm volatile("s_waitcnt vmcnt(0)" ::: "memory");
  __builtin_amdgcn_sched_barrier(0);

  // row-0 state
  float fc0 = 1.0f - bfl(q0[0]);
  float fc1 = 1.0f - bfh(q0[0]);
  float fc2 = 1.0f - bfl(q0[1]);
  float fc3 = 1.0f - bfh(q0[1]);
  q0 = aload2(gqe + (size_t)4 * SSZ);
  float lc0 = fc0, lc1 = lc0 * fc1, lc2 = lc1 * fc2;
  float lc3 = lc2 * fc3;
  float As0 = lc3;
  float As1 = As0 * f_dpp<0x111, 0xF>(As0, 1.0f);
  float As2 = As1 * f_dpp<0x112, 0xF>(As1, 1.0f);
  float As3 = As2 * f_dpp<0x114, 0xF>(As2, 1.0f);
  float As4 = As3 * f_dpp<0x118, 0xF>(As3, 1.0f);
  float As5 = As4 * f_dpp<0x142, 0xA>(As4, 1.0f);
  float A6  = As5 * f_dpp<0x143, 0xC>(As5, 1.0f);
  float wE = wave_shr1(A6, 1.0f);
  if (lane == 63) ldsAB[1][w] = make_float2(A6, 0.0f);
  asm volatile("s_waitcnt lgkmcnt(0)" ::: "memory");
  __builtin_amdgcn_s_barrier();
  __builtin_amdgcn_sched_barrier(0);
  float2 pab0 = ldsAB[1][0], pab1 = ldsAB[1][1], pab2 = ldsAB[1][2];
  float A1g = pab1.x, A2g = pab2.x;
  float Pw = 1.0f;
  if (w > 0) Pw = pab0.x;
  if (w > 1) Pw *= pab1.x;
  if (w > 2) Pw *= pab2.x;
  float c0 = (Pw * 1e6f) * wE;
  float cl0 = c0 * lc0, cl1 = c0 * lc1, cl2 = c0 * lc2;

  float prev0 = (tid == 0) ? 1.0f : 0.0f;
  float prev1 = 0.0f, prev2 = 0.0f, prev3 = 0.0f;
  f32x4 pend; pend.x = 0.0f; pend.y = 0.0f; pend.z = 0.0f; pend.w = 0.0f;
  float wsum_prev = 0.0f;

  for (int t0 = 0; t0 < TT; t0 += 4) {
    STEP(t0 + 0, q1);
    STEP(t0 + 1, q2);
    STEP(t0 + 2, q3);
    STEP(t0 + 3, q0);
  }

  asm volatile("s_waitcnt lgkmcnt(0)" ::: "memory");
  __builtin_amdgcn_s_barrier();
  __builtin_amdgcn_sched_barrier(0);
  if (tid == 255) {
    float tot = ldsS[(TT - 1) & 1][0] + ldsS[(TT - 1) & 1][1]
              + ldsS[(TT - 1) & 1][2] + wsum_prev;
    float rest = tot - pend.w;
    pend.w = 1.0f - fminf(fmaxf(rest, 0.0f), 1.0f);
    astore(gq + (size_t)(TT - 1) * SSZ, pend);
    i32x2 pk; pk[0] = cvt_pk(pend.x, pend.y); pk[1] = cvt_pk(pend.z, pend.w);
    astore2(gpb + (size_t)(TT - 1) * 32, pk);
  }
}

// ---------------- K3: X = alpha_bf16 @ V^T_bf16 via MFMA -> g_Xb ----------------
// round-11 structure; only the alpha (A-frag) loads use the k-blocked g_Pb
// layout: per kk, the wave's 64 lanes cover contiguous 1KB lines.
__global__ __launch_bounds__(256) void k_av() {
  const int tid = threadIdx.x, w = tid >> 6, l = tid & 63;
  const int rl = l & 15, kg = l >> 4;
  const int gw = blockIdx.x * 4 + w;
  const int bh = gw >> 6;
  const int t0 = (gw & 63) << 4;

  // k-blocked alpha: slot j of lane (rl,kg) at kk -> alpha[t0+rl][kk*32+kg*8+j]
  const unsigned short* ab = g_Pb + ((size_t)(bh * 32) * TT + (t0 + rl)) * 32 + (kg << 3);
  const unsigned short* vb = g_Vt + (size_t)bh * DD * SSZ;

  f32x4 acc[4];
#pragma unroll
  for (int j = 0; j < 4; ++j) acc[j] = (f32x4)0.0f;

  for (int kk = 0; kk < 32; ++kk) {
    const int kof = (kk << 5) + (kg << 3);
    s16x8 a = *(const s16x8*)(ab + (size_t)kk * TT * 32);
#pragma unroll
    for (int fj = 0; fj < 4; ++fj) {
      s16x8 b = *(const s16x8*)(vb + (size_t)(fj * 16 + rl) * SSZ + kof);
      acc[fj] = __builtin_amdgcn_mfma_f32_16x16x32_bf16(a, b, acc[fj], 0, 0, 0);
    }
  }

  const int bz = bh >> 4, hh = bh & 15;
#pragma unroll
  for (int fj = 0; fj < 4; ++fj) {
    const int d = fj * 16 + rl;
#pragma unroll
    for (int r = 0; r < 4; ++r) {
      const int t = t0 + (kg << 2) + r;
      g_Xb[((size_t)t * BSZN + bz) * EEN + hh * DD + d] = bfr(acc[fj][r]);
    }
  }
}

// ---------------- K4: Out = X_bf16 @ W_bf16^T + b via MFMA ----------------
__global__ __launch_bounds__(256) void k_out(const float* __restrict__ Bb,
                                             float* __restrict__ Out) {
  const int tid = threadIdx.x, w = tid >> 6, l = tid & 63;
  const int rl = l & 15, kg = l >> 4;
  const int gw = blockIdx.x * 4 + w;
  const int m0 = (gw >> 4) << 4;
  const int n0 = (gw & 15) << 6;

  const unsigned short* xb = g_Xb + (size_t)(m0 + rl) * EEN;

  f32x4 acc[4];
#pragma unroll
  for (int j = 0; j < 4; ++j) acc[j] = (f32x4)0.0f;

  for (int kk = 0; kk < 32; ++kk) {
    const int kof = (kk << 5) + (kg << 3);
    s16x8 a = *(const s16x8*)(xb + kof);
#pragma unroll
    for (int fj = 0; fj < 4; ++fj) {
      s16x8 b = *(const s16x8*)(g_Wb + (size_t)(n0 + fj * 16 + rl) * EEN + kof);
      acc[fj] = __builtin_amdgcn_mfma_f32_16x16x32_bf16(a, b, acc[fj], 0, 0, 0);
    }
  }

#pragma unroll
  for (int fj = 0; fj < 4; ++fj) {
    const float bias = Bb[n0 + fj * 16 + rl];
#pragma unroll
    for (int r = 0; r < 4; ++r) {
      const int m = m0 + (kg << 2) + r;
      Out[(size_t)m * EEN + n0 + fj * 16 + rl] = acc[fj][r] + bias;
    }
  }
}

extern "C" void kernel_launch(void* const* d_in, const int* in_sizes, int n_in,
                              void* d_out, int out_size, void* d_ws, size_t ws_size,
                              hipStream_t stream) {
  const float* Q  = (const float*)d_in[0];
  const float* K  = (const float*)d_in[1];
  const float* V  = (const float*)d_in[2];
  const float* W  = (const float*)d_in[3];
  const float* Bb = (const float*)d_in[4];
  const float* eb = (const float*)d_in[5];
  float* Out = (float*)d_out;
  float* Alpha = Out + (size_t)TT * BSZN * EEN;  // alpha f32 output region

  k_prep_w<<<dim3(512), dim3(256), 0, stream>>>(W);
  k_prep_v<<<dim3(BHN * 16), dim3(256), 0, stream>>>(V);
  k_energy<<<dim3(BHN * 64), dim3(256), 0, stream>>>(Q, K, eb);
  k_scan<<<dim3(BHN), dim3(256), 0, stream>>>(Alpha);
  k_av<<<dim3(1024), dim3(256), 0, stream>>>();
  k_out<<<dim3(1024), dim3(256), 0, stream>>>(Bb, Out);
}